// Round 4
// baseline (134.645 us; speedup 1.0000x reference)
//
#include <hip/hip_runtime.h>
#include <hip/hip_bf16.h>

#define LLEN 4096
#define BATCH 16
#define NROWS 65536   // BATCH*LLEN
#define DDIM 128
#define JDIM 256      // 2*D
#define KM1 255       // K-1
#define BR 64         // rows per block
#define TPITCH 264    // t LDS pitch in halfs (pad 8)
#define LOSCALE 4096.0f
#define ILO (1.0f / 4096.0f)

typedef __attribute__((ext_vector_type(8))) _Float16 h8;
typedef __attribute__((ext_vector_type(4))) _Float16 h4;
typedef __attribute__((ext_vector_type(4))) float f4v;

__device__ __forceinline__ float clampf(float x, float lo, float hi) {
  return fminf(fmaxf(x, lo), hi);
}
__device__ __forceinline__ float tanh_fast(float x) {
  float e = __expf(2.0f * x);
  return 1.0f - 2.0f / (e + 1.0f);
}

// ---------------- kW: pack W1^T, W2^T into per-wave-contiguous MFMA fragments ----------------
// W1P: 64 frag-slots [(jt*4+ks)]; W2P: 128 slots [(kt*8+ks)]. Each slot = 2048 halfs:
// [0..1023] hi plane, [1024..2047] lo plane (x4096). Within plane: lane*8+i,
// lane=(g*16+rr): value = WT[tile*16+rr][ks*32+8g+i].
__global__ void kW(const float* __restrict__ W1, const float* __restrict__ W2,
                   _Float16* __restrict__ W1P, _Float16* __restrict__ W2P) {
  const int T = blockIdx.x * 256 + threadIdx.x;   // 192 frags * 64 lanes
  if (T >= 192 * 64) return;
  const int frag = T >> 6, lane = T & 63;
  const int rr = lane & 15, g = lane >> 4;
  if (frag < 64) {
    const int jt = frag >> 2, ks = frag & 3;
    _Float16* base = W1P + (size_t)frag * 2048 + lane * 8;
    #pragma unroll
    for (int i = 0; i < 8; ++i) {
      const float v = W1[(ks * 32 + 8 * g + i) * JDIM + jt * 16 + rr];
      const _Float16 h = (_Float16)v;
      base[i] = h;
      base[1024 + i] = (_Float16)((v - (float)h) * LOSCALE);
    }
  } else {
    const int f2 = frag - 64;
    const int kt = f2 >> 3, ks = f2 & 7;
    const int k = kt * 16 + rr;
    _Float16* base = W2P + (size_t)f2 * 2048 + lane * 8;
    #pragma unroll
    for (int i = 0; i < 8; ++i) {
      const int j = ks * 32 + 8 * g + i;
      const float v = (k < KM1) ? W2[j * KM1 + k] : 0.0f;
      const _Float16 h = (_Float16)v;
      base[i] = h;
      base[1024 + i] = (_Float16)((v - (float)h) * LOSCALE);
    }
  }
}

// ---------------- kF: fused GEMM1(tanh) -> LDS t -> GEMM2 -> exp-sums ----------------
// 64 rows/block, 8 waves: mw = M-quarter (j/k), rw = row-half. One barrier total.
__launch_bounds__(512, 4)
__global__ void kF(const float* __restrict__ X,
                   const _Float16* __restrict__ W1P, const _Float16* __restrict__ W2P,
                   const float* __restrict__ b1, const float* __restrict__ Wr,
                   const float* __restrict__ mask,
                   float* __restrict__ Nsum, float* __restrict__ Dsum) {
  __shared__ _Float16 tS[BR * TPITCH];   // 33,792 B
  __shared__ float rS[BR];

  const int tid  = threadIdx.x;
  const int lane = tid & 63, wid = tid >> 6;
  const int rr = lane & 15, g = lane >> 4;
  const int mw = wid & 3;        // M quarter (j in phase1, k in phase2)
  const int rw = wid >> 2;       // row half (32 rows)
  const int blk = blockIdx.x;
  const int b = blk >> 6;        // 64 blocks per batch
  const int r_base = blk * BR;

  f4v aH[4][2], aL[4][2];
  #pragma unroll
  for (int m = 0; m < 4; ++m)
    #pragma unroll
    for (int n = 0; n < 2; ++n) {
      aH[m][n][0]=0.f; aH[m][n][1]=0.f; aH[m][n][2]=0.f; aH[m][n][3]=0.f;
      aL[m][n][0]=0.f; aL[m][n][1]=0.f; aL[m][n][2]=0.f; aL[m][n][3]=0.f;
    }
  float rp[2] = {0.f, 0.f};

  // ---- phase 1: t = tanh(X@W1+b1), M=j(256), N=rows(64), K=d(128). No barriers. ----
  for (int ks = 0; ks < 4; ++ks) {
    h8 Ah[4], Al[4];
    #pragma unroll
    for (int mf = 0; mf < 4; ++mf) {
      const _Float16* fp = W1P + ((size_t)((mw * 4 + mf) * 4 + ks)) * 2048 + lane * 8;
      Ah[mf] = *reinterpret_cast<const h8*>(fp);
      Al[mf] = *reinterpret_cast<const h8*>(fp + 1024);
    }
    float wr[8];
    {
      const float4 w0 = *reinterpret_cast<const float4*>(Wr + ks * 32 + 8 * g);
      const float4 w1 = *reinterpret_cast<const float4*>(Wr + ks * 32 + 8 * g + 4);
      wr[0]=w0.x; wr[1]=w0.y; wr[2]=w0.z; wr[3]=w0.w;
      wr[4]=w1.x; wr[5]=w1.y; wr[6]=w1.z; wr[7]=w1.w;
    }
    h8 Bx[2];
    #pragma unroll
    for (int nf = 0; nf < 2; ++nf) {
      const int r = r_base + rw * 32 + nf * 16 + rr;
      const float* xp = X + (size_t)r * DDIM + ks * 32 + 8 * g;
      const float4 x0 = *reinterpret_cast<const float4*>(xp);
      const float4 x1 = *reinterpret_cast<const float4*>(xp + 4);
      const float xv[8] = {x0.x, x0.y, x0.z, x0.w, x1.x, x1.y, x1.z, x1.w};
      #pragma unroll
      for (int i = 0; i < 8; ++i) Bx[nf][i] = (_Float16)xv[i];
      if (mw == 0) {
        #pragma unroll
        for (int i = 0; i < 8; ++i) rp[nf] += xv[i] * wr[i];
      }
    }
    #pragma unroll
    for (int mf = 0; mf < 4; ++mf)
      #pragma unroll
      for (int nf = 0; nf < 2; ++nf) {
        aH[mf][nf] = __builtin_amdgcn_mfma_f32_16x16x32_f16(Ah[mf], Bx[nf], aH[mf][nf], 0, 0, 0);
        aL[mf][nf] = __builtin_amdgcn_mfma_f32_16x16x32_f16(Al[mf], Bx[nf], aL[mf][nf], 0, 0, 0);
      }
  }

  // epilogue 1: bias + tanh -> fp16 tS; fused r-dot -> rS
  #pragma unroll
  for (int mf = 0; mf < 4; ++mf) {
    const int j0 = mw * 64 + mf * 16 + 4 * g;
    const float4 bv = *reinterpret_cast<const float4*>(b1 + j0);
    const float bva[4] = {bv.x, bv.y, bv.z, bv.w};
    #pragma unroll
    for (int nf = 0; nf < 2; ++nf) {
      const int rl = rw * 32 + nf * 16 + rr;
      h4 o;
      #pragma unroll
      for (int reg = 0; reg < 4; ++reg) {
        const float v = tanh_fast(aH[mf][nf][reg] + aL[mf][nf][reg] * ILO + bva[reg]);
        o[reg] = (_Float16)v;
      }
      *reinterpret_cast<h4*>(&tS[rl * TPITCH + j0]) = o;
    }
  }
  if (mw == 0) {
    #pragma unroll
    for (int nf = 0; nf < 2; ++nf) {
      rp[nf] += __shfl_xor(rp[nf], 16, 64);
      rp[nf] += __shfl_xor(rp[nf], 32, 64);
    }
    if (g == 0) {
      #pragma unroll
      for (int nf = 0; nf < 2; ++nf) rS[rw * 32 + nf * 16 + rr] = rp[nf];
    }
  }
  // re-zero accumulators for phase 2
  #pragma unroll
  for (int m = 0; m < 4; ++m)
    #pragma unroll
    for (int n = 0; n < 2; ++n) {
      aH[m][n][0]=0.f; aH[m][n][1]=0.f; aH[m][n][2]=0.f; aH[m][n][3]=0.f;
      aL[m][n][0]=0.f; aL[m][n][1]=0.f; aL[m][n][2]=0.f; aL[m][n][3]=0.f;
    }
  __syncthreads();   // the only barrier

  // ---- phase 2: logits = t@W2, M=k(256), N=rows(64), K=j(256). No barriers. ----
  for (int ks = 0; ks < 8; ++ks) {
    h8 Ah[4], Al[4], Bt[2];
    #pragma unroll
    for (int mf = 0; mf < 4; ++mf) {
      const _Float16* fp = W2P + ((size_t)((mw * 4 + mf) * 8 + ks)) * 2048 + lane * 8;
      Ah[mf] = *reinterpret_cast<const h8*>(fp);
      Al[mf] = *reinterpret_cast<const h8*>(fp + 1024);
    }
    #pragma unroll
    for (int nf = 0; nf < 2; ++nf) {
      const int rl = rw * 32 + nf * 16 + rr;
      Bt[nf] = *reinterpret_cast<const h8*>(&tS[rl * TPITCH + ks * 32 + 8 * g]);
    }
    #pragma unroll
    for (int mf = 0; mf < 4; ++mf)
      #pragma unroll
      for (int nf = 0; nf < 2; ++nf) {
        aH[mf][nf] = __builtin_amdgcn_mfma_f32_16x16x32_f16(Ah[mf], Bt[nf], aH[mf][nf], 0, 0, 0);
        aL[mf][nf] = __builtin_amdgcn_mfma_f32_16x16x32_f16(Al[mf], Bt[nf], aL[mf][nf], 0, 0, 0);
      }
  }

  // epilogue 2: masked exp; per-k sums of e and e*r; atomics
  float sE[4][4], sR[4][4];
  #pragma unroll
  for (int mf = 0; mf < 4; ++mf)
    #pragma unroll
    for (int reg = 0; reg < 4; ++reg) { sE[mf][reg] = 0.f; sR[mf][reg] = 0.f; }
  #pragma unroll
  for (int nf = 0; nf < 2; ++nf) {
    const int rl = rw * 32 + nf * 16 + rr;
    const int rg = r_base + rl;
    const float mv = mask[rg];
    const float rv = rS[rl];
    const float addm = (1.0f - mv) * (-1e30f);
    #pragma unroll
    for (int mf = 0; mf < 4; ++mf)
      #pragma unroll
      for (int reg = 0; reg < 4; ++reg) {
        const float logit = aH[mf][nf][reg] + aL[mf][nf][reg] * ILO;
        const float e = __expf(mv * logit + addm);
        sE[mf][reg] += e;
        sR[mf][reg] += e * rv;
      }
  }
  #pragma unroll
  for (int off = 1; off < 16; off <<= 1)
    #pragma unroll
    for (int mf = 0; mf < 4; ++mf)
      #pragma unroll
      for (int reg = 0; reg < 4; ++reg) {
        sE[mf][reg] += __shfl_xor(sE[mf][reg], off, 64);
        sR[mf][reg] += __shfl_xor(sR[mf][reg], off, 64);
      }
  if (rr == 0) {
    #pragma unroll
    for (int mf = 0; mf < 4; ++mf)
      #pragma unroll
      for (int reg = 0; reg < 4; ++reg) {
        const int k = mw * 64 + mf * 16 + 4 * g + reg;
        atomicAdd(&Dsum[b * 256 + k], sE[mf][reg]);
        atomicAdd(&Nsum[b * 256 + k], sR[mf][reg]);
      }
  }
}

// ---------------- kC: mu -> softmax -> cumsum -> cdf params ----------------
__global__ void kC(const float* __restrict__ Nsum, const float* __restrict__ Dsum,
                   const float* __restrict__ br, float* __restrict__ params) {
  __shared__ float red[256];
  __shared__ float sm[256];
  const int b = blockIdx.x;
  const int k = threadIdx.x;
  float v = 0.0f;
  if (k > 0) v = Nsum[b * 256 + (k - 1)] / Dsum[b * 256 + (k - 1)] + br[0];
  red[k] = v; __syncthreads();
  #pragma unroll
  for (int off = 128; off > 0; off >>= 1) {
    if (k < off) red[k] = fmaxf(red[k], red[k + off]);
    __syncthreads();
  }
  const float vmax = red[0];
  __syncthreads();
  const float e = expf(v - vmax);
  red[k] = e; __syncthreads();
  #pragma unroll
  for (int off = 128; off > 0; off >>= 1) {
    if (k < off) red[k] += red[k + off];
    __syncthreads();
  }
  const float tot = red[0];
  __syncthreads();
  sm[k] = e / tot; __syncthreads();
  for (int off = 1; off < 256; off <<= 1) {
    const float add = (k >= off) ? sm[k - off] : 0.0f;
    __syncthreads();
    sm[k] += add;
    __syncthreads();
  }
  if (k < KM1) {
    const float m  = clampf(sm[k], 1e-4f, 0.9999f);
    const float a  = clampf(m - 0.0625f, 0.0f, 0.875f);
    const float bb = clampf(a + 0.125f, 0.125f, 1.0f);
    const float ba = bb - a, ma = m - a, bm = bb - m;
    float* p = params + ((size_t)b * KM1 + k) * 8;
    *reinterpret_cast<float4*>(p)     = make_float4(m, a, bb, ma / ba);
    *reinterpret_cast<float4*>(p + 4) = make_float4(1.0f / ma, bm / ba, 1.0f / bm, 0.0f);
  }
}

// ---------------- kD: gamma_scaled + almat ----------------
__launch_bounds__(256)
__global__ void kD(const float* __restrict__ params, float* __restrict__ gamma,
                   float* __restrict__ almat) {
  __shared__ float P[KM1][8];
  __shared__ float gl[256];
  const int lc = blockIdx.x, b = blockIdx.y;
  const int tid = threadIdx.x;
  if (tid < KM1) {
    const float* p = params + ((size_t)b * KM1 + tid) * 8;
    *reinterpret_cast<float4*>(&P[tid][0]) = *reinterpret_cast<const float4*>(p);
    *reinterpret_cast<float4*>(&P[tid][4]) = *reinterpret_cast<const float4*>(p + 4);
  }
  __syncthreads();
  const int l = lc * 256 + tid;
  const float x = (float)l * (1.0f / 4095.0f);
  float g = 0.0f;
  for (int k = 0; k < KM1; ++k) {
    const float m = P[k][0], a = P[k][1], bb = P[k][2], cL = P[k][3];
    const float iMA = P[k][4], cR = P[k][5], iBM = P[k][6];
    float u = clampf((x - a) * iMA, 0.0f, 1.0f);
    u = u * u; u = u * u; u = u * u; u = u * u;
    float w = clampf((bb - x) * iBM, 0.0f, 1.0f);
    w = w * w; w = w * w; w = w * w; w = w * w;
    const float left  = cL * u;
    const float right = 1.0f - cR * w;
    g += (x <= m) ? left : right;
  }
  gamma[(size_t)b * LLEN + l] = g;
  gl[tid] = g;
  __syncthreads();
  const size_t base = ((size_t)b * LLEN + (size_t)lc * 256) * 256;
  for (int i = 0; i < 256; ++i) {
    const float gv = gl[i];
    const float val = fmaxf(1.0f - fabsf(gv - (float)tid), 0.0f);
    almat[base + (size_t)i * 256 + tid] = val;
  }
}

extern "C" void kernel_launch(void* const* d_in, const int* in_sizes, int n_in,
                              void* d_out, int out_size, void* d_ws, size_t ws_size,
                              hipStream_t stream) {
  const float* X    = (const float*)d_in[0];
  const float* mask = (const float*)d_in[1];
  const float* W1   = (const float*)d_in[2];
  const float* b1   = (const float*)d_in[3];
  const float* W2   = (const float*)d_in[4];
  const float* Wr   = (const float*)d_in[5];
  const float* br   = (const float*)d_in[6];
  float* out   = (float*)d_out;
  float* gamma = out;
  float* almat = out + NROWS;
  // workspace
  float* Nsum = (float*)d_ws;                        // [16][256]
  float* Dsum = Nsum + BATCH * 256;                  // [16][256]
  float* params = Dsum + BATCH * 256;                // [16][255][8]
  _Float16* W1P = (_Float16*)(params + (size_t)BATCH * KM1 * 8); // 64*2048 halfs
  _Float16* W2P = W1P + 64 * 2048;                               // 128*2048 halfs

  hipMemsetAsync(d_ws, 0, (size_t)BATCH * 256 * 2 * sizeof(float), stream);
  kW<<<48, 256, 0, stream>>>(W1, W2, W1P, W2P);
  kF<<<NROWS / BR, 512, 0, stream>>>(X, W1P, W2P, b1, Wr, mask, Nsum, Dsum);
  kC<<<BATCH, 256, 0, stream>>>(Nsum, Dsum, br, params);
  kD<<<dim3(16, BATCH), 256, 0, stream>>>(params, gamma, almat);
}

// Round 5
// 108.384 us; speedup vs baseline: 1.2423x; 1.2423x over previous
//
#include <hip/hip_runtime.h>
#include <hip/hip_bf16.h>

#define LLEN 4096
#define BATCH 16
#define NROWS 65536   // BATCH*LLEN
#define DDIM 128
#define JDIM 256      // 2*D
#define KM1 255       // K-1
#define BR 64         // rows per block
#define TPITCH 266    // t LDS pitch in halfs (133 dwords -> odd bank stride)

typedef __attribute__((ext_vector_type(8))) _Float16 h8;
typedef __attribute__((ext_vector_type(4))) _Float16 h4;
typedef __attribute__((ext_vector_type(4))) float f4v;

__device__ __forceinline__ float clampf(float x, float lo, float hi) {
  return fminf(fmaxf(x, lo), hi);
}
__device__ __forceinline__ float tanh_fast(float x) {
  float e = __expf(2.0f * x);
  return 1.0f - 2.0f / (e + 1.0f);
}

// ---------------- kW: pack W1^T, W2^T into per-wave-contiguous fp16 MFMA fragments ----------------
// frag = 64 lanes x 8 halfs (1 KB). lane=(g*16+rr): value = WT[tile*16+rr][ks*32+8g+i].
// W1P: frag (jt*4+ks), jt<16, ks<4. W2P: frag (kt*8+ks), kt<16, ks<8 (k=255 zero-pad).
__global__ void kW(const float* __restrict__ W1, const float* __restrict__ W2,
                   _Float16* __restrict__ W1P, _Float16* __restrict__ W2P) {
  const int T = blockIdx.x * 256 + threadIdx.x;   // 192 frags * 64 lanes
  if (T >= 192 * 64) return;
  const int frag = T >> 6, lane = T & 63;
  const int rr = lane & 15, g = lane >> 4;
  if (frag < 64) {
    const int jt = frag >> 2, ks = frag & 3;
    _Float16* base = W1P + (size_t)frag * 512 + lane * 8;
    #pragma unroll
    for (int i = 0; i < 8; ++i)
      base[i] = (_Float16)W1[(ks * 32 + 8 * g + i) * JDIM + jt * 16 + rr];
  } else {
    const int f2 = frag - 64;
    const int kt = f2 >> 3, ks = f2 & 7;
    const int k = kt * 16 + rr;
    _Float16* base = W2P + (size_t)f2 * 512 + lane * 8;
    #pragma unroll
    for (int i = 0; i < 8; ++i)
      base[i] = (k < KM1) ? (_Float16)W2[(ks * 32 + 8 * g + i) * KM1 + k] : (_Float16)0.0f;
  }
}

// ---------------- kF: fused GEMM1(tanh) -> LDS t -> GEMM2 -> exp partial sums ----------------
// 64 rows/block, 8 waves: mw = M-quarter (j/k), rw = row-half. One barrier. No atomics.
__launch_bounds__(512, 4)
__global__ void kF(const float* __restrict__ X,
                   const _Float16* __restrict__ W1P, const _Float16* __restrict__ W2P,
                   const float* __restrict__ b1, const float* __restrict__ Wr,
                   const float* __restrict__ mask,
                   float* __restrict__ partE, float* __restrict__ partR) {
  __shared__ _Float16 tS[BR * TPITCH];   // 34,048 B
  __shared__ float rS[BR];

  const int tid  = threadIdx.x;
  const int lane = tid & 63, wid = tid >> 6;
  const int rr = lane & 15, g = lane >> 4;
  const int mw = wid & 3;        // M quarter (j in phase1, k in phase2)
  const int rw = wid >> 2;       // row half (32 rows)
  const int blk = blockIdx.x;
  const int b = blk >> 6;        // 64 blocks per batch
  const int r_base = blk * BR;

  f4v acc[4][2];
  #pragma unroll
  for (int m = 0; m < 4; ++m)
    #pragma unroll
    for (int n = 0; n < 2; ++n) { acc[m][n][0]=0.f; acc[m][n][1]=0.f; acc[m][n][2]=0.f; acc[m][n][3]=0.f; }
  float rp[2] = {0.f, 0.f};

  // ---- phase 1: t = tanh(X@W1+b1), M=j(256), N=rows(64), K=d(128). Pipelined, no barriers. ----
  h8 Wc[4], Wn[4];
  #pragma unroll
  for (int mf = 0; mf < 4; ++mf)
    Wc[mf] = *reinterpret_cast<const h8*>(W1P + (size_t)((mw * 4 + mf) * 4) * 512 + lane * 8);
  float4 xc[2][2], xn[2][2];
  #pragma unroll
  for (int nf = 0; nf < 2; ++nf) {
    const float* xp = X + (size_t)(r_base + rw * 32 + nf * 16 + rr) * DDIM + 8 * g;
    xc[nf][0] = *reinterpret_cast<const float4*>(xp);
    xc[nf][1] = *reinterpret_cast<const float4*>(xp + 4);
  }
  #pragma unroll
  for (int ks = 0; ks < 4; ++ks) {
    if (ks < 3) {
      #pragma unroll
      for (int mf = 0; mf < 4; ++mf)
        Wn[mf] = *reinterpret_cast<const h8*>(W1P + (size_t)((mw * 4 + mf) * 4 + ks + 1) * 512 + lane * 8);
      #pragma unroll
      for (int nf = 0; nf < 2; ++nf) {
        const float* xp = X + (size_t)(r_base + rw * 32 + nf * 16 + rr) * DDIM + (ks + 1) * 32 + 8 * g;
        xn[nf][0] = *reinterpret_cast<const float4*>(xp);
        xn[nf][1] = *reinterpret_cast<const float4*>(xp + 4);
      }
    }
    h8 Bx[2];
    #pragma unroll
    for (int nf = 0; nf < 2; ++nf) {
      const float xv[8] = {xc[nf][0].x, xc[nf][0].y, xc[nf][0].z, xc[nf][0].w,
                           xc[nf][1].x, xc[nf][1].y, xc[nf][1].z, xc[nf][1].w};
      #pragma unroll
      for (int i = 0; i < 8; ++i) Bx[nf][i] = (_Float16)xv[i];
      if (mw == 0) {
        const float4 w0 = *reinterpret_cast<const float4*>(Wr + ks * 32 + 8 * g);
        const float4 w1 = *reinterpret_cast<const float4*>(Wr + ks * 32 + 8 * g + 4);
        rp[nf] += xv[0]*w0.x + xv[1]*w0.y + xv[2]*w0.z + xv[3]*w0.w
                + xv[4]*w1.x + xv[5]*w1.y + xv[6]*w1.z + xv[7]*w1.w;
      }
    }
    #pragma unroll
    for (int mf = 0; mf < 4; ++mf)
      #pragma unroll
      for (int nf = 0; nf < 2; ++nf)
        acc[mf][nf] = __builtin_amdgcn_mfma_f32_16x16x32_f16(Wc[mf], Bx[nf], acc[mf][nf], 0, 0, 0);
    if (ks < 3) {
      #pragma unroll
      for (int mf = 0; mf < 4; ++mf) Wc[mf] = Wn[mf];
      #pragma unroll
      for (int nf = 0; nf < 2; ++nf) { xc[nf][0] = xn[nf][0]; xc[nf][1] = xn[nf][1]; }
    }
  }

  // epilogue 1: bias + tanh -> fp16 tS; fused r-dot -> rS
  #pragma unroll
  for (int mf = 0; mf < 4; ++mf) {
    const int j0 = (mw * 4 + mf) * 16 + 4 * g;
    const float4 bv = *reinterpret_cast<const float4*>(b1 + j0);
    const float bva[4] = {bv.x, bv.y, bv.z, bv.w};
    #pragma unroll
    for (int nf = 0; nf < 2; ++nf) {
      const int rl = rw * 32 + nf * 16 + rr;
      h4 o;
      #pragma unroll
      for (int reg = 0; reg < 4; ++reg)
        o[reg] = (_Float16)tanh_fast(acc[mf][nf][reg] + bva[reg]);
      *reinterpret_cast<h4*>(&tS[rl * TPITCH + j0]) = o;
    }
  }
  if (mw == 0) {
    #pragma unroll
    for (int nf = 0; nf < 2; ++nf) {
      rp[nf] += __shfl_xor(rp[nf], 16, 64);
      rp[nf] += __shfl_xor(rp[nf], 32, 64);
    }
    if (g == 0) {
      #pragma unroll
      for (int nf = 0; nf < 2; ++nf) rS[rw * 32 + nf * 16 + rr] = rp[nf];
    }
  }
  // re-zero accumulators for phase 2
  #pragma unroll
  for (int m = 0; m < 4; ++m)
    #pragma unroll
    for (int n = 0; n < 2; ++n) { acc[m][n][0]=0.f; acc[m][n][1]=0.f; acc[m][n][2]=0.f; acc[m][n][3]=0.f; }
  __syncthreads();   // the only barrier

  // ---- phase 2: logits = t@W2, M=k(256), N=rows(64), K=j(256). Pipelined, no barriers. ----
  #pragma unroll
  for (int mf = 0; mf < 4; ++mf)
    Wc[mf] = *reinterpret_cast<const h8*>(W2P + (size_t)((mw * 4 + mf) * 8) * 512 + lane * 8);
  #pragma unroll
  for (int ks = 0; ks < 8; ++ks) {
    if (ks < 7) {
      #pragma unroll
      for (int mf = 0; mf < 4; ++mf)
        Wn[mf] = *reinterpret_cast<const h8*>(W2P + (size_t)((mw * 4 + mf) * 8 + ks + 1) * 512 + lane * 8);
    }
    h8 Bt[2];
    #pragma unroll
    for (int nf = 0; nf < 2; ++nf) {
      const int rl = rw * 32 + nf * 16 + rr;
      Bt[nf] = *reinterpret_cast<const h8*>(&tS[rl * TPITCH + ks * 32 + 8 * g]);
    }
    #pragma unroll
    for (int mf = 0; mf < 4; ++mf)
      #pragma unroll
      for (int nf = 0; nf < 2; ++nf)
        acc[mf][nf] = __builtin_amdgcn_mfma_f32_16x16x32_f16(Wc[mf], Bt[nf], acc[mf][nf], 0, 0, 0);
    if (ks < 7) {
      #pragma unroll
      for (int mf = 0; mf < 4; ++mf) Wc[mf] = Wn[mf];
    }
  }

  // epilogue 2: masked exp; per-k sums of e and e*r over this wave's 32 rows; partial write
  float sE[4][4], sR[4][4];
  #pragma unroll
  for (int mf = 0; mf < 4; ++mf)
    #pragma unroll
    for (int reg = 0; reg < 4; ++reg) { sE[mf][reg] = 0.f; sR[mf][reg] = 0.f; }
  #pragma unroll
  for (int nf = 0; nf < 2; ++nf) {
    const int rl = rw * 32 + nf * 16 + rr;
    const int rg = r_base + rl;
    const float mv = mask[rg];
    const float rv = rS[rl];
    const float addm = (1.0f - mv) * (-1e30f);
    #pragma unroll
    for (int mf = 0; mf < 4; ++mf)
      #pragma unroll
      for (int reg = 0; reg < 4; ++reg) {
        const float e = __expf(mv * acc[mf][nf][reg] + addm);
        sE[mf][reg] += e;
        sR[mf][reg] += e * rv;
      }
  }
  #pragma unroll
  for (int off = 1; off < 16; off <<= 1)
    #pragma unroll
    for (int mf = 0; mf < 4; ++mf)
      #pragma unroll
      for (int reg = 0; reg < 4; ++reg) {
        sE[mf][reg] += __shfl_xor(sE[mf][reg], off, 64);
        sR[mf][reg] += __shfl_xor(sR[mf][reg], off, 64);
      }
  if (rr == 0) {
    const int s = (blk & 63) * 2 + rw;            // 0..127 within batch
    float* pE = partE + (size_t)s * 4096 + b * 256;
    float* pR = partR + (size_t)s * 4096 + b * 256;
    #pragma unroll
    for (int mf = 0; mf < 4; ++mf)
      #pragma unroll
      for (int reg = 0; reg < 4; ++reg) {
        const int k = (mw * 4 + mf) * 16 + 4 * g + reg;
        pE[k] = sE[mf][reg];
        pR[k] = sR[mf][reg];
      }
  }
}

// ---------------- kC: reduce partials -> mu -> softmax -> cumsum -> cdf params ----------------
__global__ void kC(const float* __restrict__ partE, const float* __restrict__ partR,
                   const float* __restrict__ br, float* __restrict__ params) {
  __shared__ float red[256];
  __shared__ float sm[256];
  const int b = blockIdx.x;
  const int k = threadIdx.x;
  float v = 0.0f;
  if (k > 0) {
    float e = 0.0f, r = 0.0f;
    for (int s = 0; s < 128; ++s) {
      e += partE[(size_t)s * 4096 + b * 256 + (k - 1)];
      r += partR[(size_t)s * 4096 + b * 256 + (k - 1)];
    }
    v = r / e + br[0];
  }
  red[k] = v; __syncthreads();
  #pragma unroll
  for (int off = 128; off > 0; off >>= 1) {
    if (k < off) red[k] = fmaxf(red[k], red[k + off]);
    __syncthreads();
  }
  const float vmax = red[0];
  __syncthreads();
  const float e = expf(v - vmax);
  red[k] = e; __syncthreads();
  #pragma unroll
  for (int off = 128; off > 0; off >>= 1) {
    if (k < off) red[k] += red[k + off];
    __syncthreads();
  }
  const float tot = red[0];
  __syncthreads();
  sm[k] = e / tot; __syncthreads();
  for (int off = 1; off < 256; off <<= 1) {
    const float add = (k >= off) ? sm[k - off] : 0.0f;
    __syncthreads();
    sm[k] += add;
    __syncthreads();
  }
  if (k < KM1) {
    const float m  = clampf(sm[k], 1e-4f, 0.9999f);
    const float a  = clampf(m - 0.0625f, 0.0f, 0.875f);
    const float bb = clampf(a + 0.125f, 0.125f, 1.0f);
    const float ba = bb - a, ma = m - a, bm = bb - m;
    float* p = params + ((size_t)b * KM1 + k) * 8;
    *reinterpret_cast<float4*>(p)     = make_float4(m, a, bb, ma / ba);
    *reinterpret_cast<float4*>(p + 4) = make_float4(1.0f / ma, bm / ba, 1.0f / bm, 0.0f);
  }
}

// ---------------- kD: gamma_scaled + almat (float4 stores) ----------------
__launch_bounds__(256)
__global__ void kD(const float* __restrict__ params, float* __restrict__ gamma,
                   float* __restrict__ almat) {
  __shared__ float P[KM1][8];
  __shared__ float gl[256];
  const int lc = blockIdx.x, b = blockIdx.y;
  const int tid = threadIdx.x;
  if (tid < KM1) {
    const float* p = params + ((size_t)b * KM1 + tid) * 8;
    *reinterpret_cast<float4*>(&P[tid][0]) = *reinterpret_cast<const float4*>(p);
    *reinterpret_cast<float4*>(&P[tid][4]) = *reinterpret_cast<const float4*>(p + 4);
  }
  __syncthreads();
  const int l = lc * 256 + tid;
  const float x = (float)l * (1.0f / 4095.0f);
  float g = 0.0f;
  for (int k = 0; k < KM1; ++k) {
    const float m = P[k][0], a = P[k][1], bb = P[k][2], cL = P[k][3];
    const float iMA = P[k][4], cR = P[k][5], iBM = P[k][6];
    float u = clampf((x - a) * iMA, 0.0f, 1.0f);
    u = u * u; u = u * u; u = u * u; u = u * u;
    float w = clampf((bb - x) * iBM, 0.0f, 1.0f);
    w = w * w; w = w * w; w = w * w; w = w * w;
    const float left  = cL * u;
    const float right = 1.0f - cR * w;
    g += (x <= m) ? left : right;
  }
  gamma[(size_t)b * LLEN + l] = g;
  gl[tid] = g;
  __syncthreads();
  // almat: thread -> 4 consecutive k, 64 i-steps; wave writes 1 KB contiguous
  const int kg = (tid & 63) * 4;
  const int i0 = tid >> 6;
  const float kg0 = (float)kg;
  const size_t base = ((size_t)b * LLEN + (size_t)lc * 256) * 256;
  for (int s = 0; s < 64; ++s) {
    const int i = s * 4 + i0;
    const float gv = gl[i];
    float4 v;
    v.x = fmaxf(1.0f - fabsf(gv - kg0), 0.0f);
    v.y = fmaxf(1.0f - fabsf(gv - (kg0 + 1.0f)), 0.0f);
    v.z = fmaxf(1.0f - fabsf(gv - (kg0 + 2.0f)), 0.0f);
    v.w = fmaxf(1.0f - fabsf(gv - (kg0 + 3.0f)), 0.0f);
    *reinterpret_cast<float4*>(&almat[base + (size_t)i * 256 + kg]) = v;
  }
}

extern "C" void kernel_launch(void* const* d_in, const int* in_sizes, int n_in,
                              void* d_out, int out_size, void* d_ws, size_t ws_size,
                              hipStream_t stream) {
  const float* X    = (const float*)d_in[0];
  const float* mask = (const float*)d_in[1];
  const float* W1   = (const float*)d_in[2];
  const float* b1   = (const float*)d_in[3];
  const float* W2   = (const float*)d_in[4];
  const float* Wr   = (const float*)d_in[5];
  const float* br   = (const float*)d_in[6];
  float* out   = (float*)d_out;
  float* gamma = out;
  float* almat = out + NROWS;
  // partial sums aliased in almat region (overwritten by kD afterwards):
  float* partE = almat;                    // [128][4096] f32 = 2 MB
  float* partR = almat + (size_t)128 * 4096;
  // workspace
  float* params = (float*)d_ws;                                  // [16][255][8]
  _Float16* W1P = (_Float16*)(params + (size_t)BATCH * KM1 * 8); // 64 frags * 512 halfs
  _Float16* W2P = W1P + 64 * 512;                                // 128 frags * 512 halfs

  kW<<<48, 256, 0, stream>>>(W1, W2, W1P, W2P);
  kF<<<NROWS / BR, 512, 0, stream>>>(X, W1P, W2P, b1, Wr, mask, partE, partR);
  kC<<<BATCH, 256, 0, stream>>>(partE, partR, br, params);
  kD<<<dim3(16, BATCH), 256, 0, stream>>>(params, gamma, almat);
}